// Round 1
// baseline (561.954 us; speedup 1.0000x reference)
//
#include <hip/hip_runtime.h>

namespace {

constexpr int Gg     = 160;
constexpr int NA     = 3;
constexpr int NB     = 16;
constexpr int CP     = 86;          // channels per anchor: 6 + 80
constexpr int NCLS   = 80;
constexpr int PLANE  = Gg * Gg;     // 25600
constexpr int QPP    = PLANE / 4;   // 6400 quads per (b,a) plane
constexpr int TOTAL  = NB * NA * QPP;
constexpr float STRIDE = 8.0f;      // 1280 / 160

union F4 { float4 v; float f[4]; };

__device__ __forceinline__ float4 ld4(const float* p) {
    return *reinterpret_cast<const float4*>(p);
}

__device__ __forceinline__ float fsigmoid(float v) {
    // 1/(1+e^-v) with fast exp + hw rcp; abs threshold is ~135, this is safe.
    return __builtin_amdgcn_rcpf(1.0f + __expf(-v));
}

__global__ __launch_bounds__(256) void anchor_decode(
    const float* __restrict__ x,
    const float* __restrict__ anchors,
    float* __restrict__ out)
{
    const int t = blockIdx.x * 256 + threadIdx.x;
    if (t >= TOTAL) return;

    const int q   = t % QPP;
    const int ba  = t / QPP;           // b*NA + a
    const int a   = ba % NA;
    const int pix = q * 4;
    const int i   = pix / Gg;          // grid_y
    const int j   = pix - i * Gg;      // grid_x of first pixel (row-aligned: 160%4==0)

    const float* xp = x + (size_t)ba * CP * PLANE + pix;

    // head channels 0..5
    F4 c0, c1, c2, c3, c4, c5;
    c0.v = ld4(xp + 0 * PLANE);
    c1.v = ld4(xp + 1 * PLANE);
    c2.v = ld4(xp + 2 * PLANE);
    c3.v = ld4(xp + 3 * PLANE);
    c4.v = ld4(xp + 4 * PLANE);
    c5.v = ld4(xp + 5 * PLANE);

    // running argmax over class channels 6..85 (strict > keeps first max, numpy semantics)
    F4 best; best.v = ld4(xp + 6 * PLANE);
    float bidx[4] = {0.f, 0.f, 0.f, 0.f};
    #pragma unroll 8
    for (int c = 1; c < NCLS; ++c) {
        F4 u; u.v = ld4(xp + (size_t)(6 + c) * PLANE);
        #pragma unroll
        for (int p = 0; p < 4; ++p) {
            const bool gt = u.f[p] > best.f[p];
            best.f[p] = gt ? u.f[p] : best.f[p];
            bidx[p]   = gt ? (float)c : bidx[p];
        }
    }

    const float aw = anchors[a * 2 + 0];
    const float ah = anchors[a * 2 + 1];
    const float fi = (float)i;
    const float fj = (float)j;

    alignas(16) float fout[28];
    #pragma unroll
    for (int p = 0; p < 4; ++p) {
        fout[p * 7 + 0] = floorf((fsigmoid(c0.f[p]) + (fj + (float)p)) * STRIDE);
        fout[p * 7 + 1] = floorf((fsigmoid(c1.f[p]) + fi) * STRIDE);
        fout[p * 7 + 2] = __expf(c2.f[p]) * aw;
        fout[p * 7 + 3] = __expf(c3.f[p]) * ah;
        fout[p * 7 + 4] = c4.f[p];
        fout[p * 7 + 5] = fsigmoid(c5.f[p]);
        fout[p * 7 + 6] = bidx[p];
    }

    // 28 contiguous floats, byte offset = (ba*PLANE+pix)*28 with pix%4==0 -> 16B aligned
    float* op = out + (size_t)(ba * PLANE + pix) * 7;
    #pragma unroll
    for (int k = 0; k < 7; ++k) {
        *reinterpret_cast<float4*>(op + k * 4) =
            *reinterpret_cast<float4*>(&fout[k * 4]);
    }
}

} // namespace

extern "C" void kernel_launch(void* const* d_in, const int* in_sizes, int n_in,
                              void* d_out, int out_size, void* d_ws, size_t ws_size,
                              hipStream_t stream) {
    const float* x       = (const float*)d_in[0];
    // d_in[1] (target) is unused by the reference output
    const float* anchors = (const float*)d_in[2];
    float* out           = (float*)d_out;

    const int blocks = (TOTAL + 255) / 256;  // 1200
    anchor_decode<<<blocks, 256, 0, stream>>>(x, anchors, out);
}